// Round 4
// baseline (438.059 us; speedup 1.0000x reference)
//
#include <hip/hip_runtime.h>

// LIF + WTA forward. Key observation: spikes are binary {0,1}, so the
// per-group top-k threshold (thr in {0,1}) mask is an exact identity on the
// forward spike values (sg*mask == sg in both cases). The whole op reduces to
// a pure elementwise kernel:
//   v = beta[col]*v_prev + input; s = (v>=1); v -= s; out = concat(v, s).
// Memory-bound: ~512 MB traffic/call -> ~81 us floor at 6.3 TB/s.

#define LIF_SIZE 8192

__global__ __launch_bounds__(256) void WTALayer_15831249453638_kernel(
    const float* __restrict__ input_current,
    const float* __restrict__ v_prev,
    const float* __restrict__ beta,
    float* __restrict__ v_out,
    float* __restrict__ s_out,
    int n4)
{
    const float4* __restrict__ ic4 = reinterpret_cast<const float4*>(input_current);
    const float4* __restrict__ vp4 = reinterpret_cast<const float4*>(v_prev);
    float4* __restrict__ vo4 = reinterpret_cast<float4*>(v_out);
    float4* __restrict__ so4 = reinterpret_cast<float4*>(s_out);

    const int stride = gridDim.x * blockDim.x;
    for (int i = blockIdx.x * blockDim.x + threadIdx.x; i < n4; i += stride) {
        float4 ic = ic4[i];
        float4 vp = vp4[i];
        // column within the row; SIZE=8192 is a multiple of 4 so the 4 lanes
        // of this float4 are contiguous columns -> one float4 beta load.
        const int col = (i << 2) & (LIF_SIZE - 1);
        float4 b = *reinterpret_cast<const float4*>(beta + col);

        float4 v, s;
        v.x = fmaf(b.x, vp.x, ic.x);
        v.y = fmaf(b.y, vp.y, ic.y);
        v.z = fmaf(b.z, vp.z, ic.z);
        v.w = fmaf(b.w, vp.w, ic.w);

        s.x = (v.x >= 1.0f) ? 1.0f : 0.0f;
        s.y = (v.y >= 1.0f) ? 1.0f : 0.0f;
        s.z = (v.z >= 1.0f) ? 1.0f : 0.0f;
        s.w = (v.w >= 1.0f) ? 1.0f : 0.0f;

        v.x -= s.x;
        v.y -= s.y;
        v.z -= s.z;
        v.w -= s.w;

        vo4[i] = v;
        so4[i] = s;
    }
}

extern "C" void kernel_launch(void* const* d_in, const int* in_sizes, int n_in,
                              void* d_out, int out_size, void* d_ws, size_t ws_size,
                              hipStream_t stream) {
    const float* input_current = (const float*)d_in[0];
    const float* v_prev        = (const float*)d_in[1];
    const float* beta          = (const float*)d_in[2];

    const int n_elems = in_sizes[0];           // B * SIZE = 33,554,432
    const int n4 = n_elems >> 2;               // 8,388,608 float4s

    float* v_out = (float*)d_out;              // first B*SIZE floats
    float* s_out = (float*)d_out + n_elems;    // second B*SIZE floats

    // 2048 blocks x 256 threads = 8 blocks/CU on 256 CUs; grid-stride covers
    // the rest (16 float4 iterations/thread).
    const int block = 256;
    const int grid = 2048;
    WTALayer_15831249453638_kernel<<<grid, block, 0, stream>>>(
        input_current, v_prev, beta, v_out, s_out, n4);
}